// Round 4
// baseline (421.774 us; speedup 1.0000x reference)
//
#include <hip/hip_runtime.h>

// y = irfft(rfft(x, axis=1, ortho) * H, n=T, axis=1, ortho)
// x: [8, 8192, 512] f32, H: [512, 4097, 2] f32, y: [8, 8192, 512] f32
//
// Round 4: Bailey 4-step, 8192 = 64 * 128, t = 128*t1 + t2, k = k1 + 64*k2.
//   K1: A[b,k1,t2,j] = sum_t1 z[b,128*t1+t2,j] w64^{-t1 k1} * w8192^{-t2 k1}
//       (z = packed complex of f-pair j; FFT64 = dft8 x dft8 via LDS)
//   K2: per (b, {k1,64-k1}, 32 j): FFT128 over t2 (dft16 x dft8), untangle
//       real-pair spectra, filter (1/8192 folded), repack, iFFT128,
//       * w8192^{+t2 k1}, in-place in ws.
//   K3: z[b,t,j] = sum_k1 B[b,k1,t2,j] w64^{+t1 k1}; store y.
// All global accesses are contiguous 512B (or 256B) wave transactions.

#define TWO_PI 6.28318530717958647692f
#define FREQ 4097

__device__ __forceinline__ float2 cmul(float2 a, float2 b) {
    return make_float2(a.x * b.x - a.y * b.y, a.x * b.y + a.y * b.x);
}

#define BF1(i0, i1) { float2 a = v[i0], b = v[i1]; \
    v[i0] = make_float2(a.x + b.x, a.y + b.y); \
    v[i1] = make_float2(a.x - b.x, a.y - b.y); }
#define BFI(i0, i1) { float2 a = v[i0], b = v[i1]; \
    v[i0] = make_float2(a.x + b.x, a.y + b.y); \
    float dr = a.x - b.x, di = a.y - b.y; \
    v[i1] = make_float2(-di * S, dr * S); }
#define BFW(i0, i1, wr, wi) { float2 a = v[i0], b = v[i1]; \
    v[i0] = make_float2(a.x + b.x, a.y + b.y); \
    float dr = a.x - b.x, di = a.y - b.y; \
    v[i1] = make_float2(dr * (wr) - di * (wi), dr * (wi) + di * (wr)); }

// 8-pt DFT, natural in, out v[p] = X[rev3(p)]; SGN=-1 fwd, +1 inv
template<int SGN>
__device__ __forceinline__ void dft8(float2* v) {
    constexpr float S  = (float)SGN;
    constexpr float RT = 0.70710678118654752440f;
    BF1(0, 4); BFW(1, 5, RT, S * RT); BFI(2, 6); BFW(3, 7, -RT, S * RT);
    BF1(0, 2); BFI(1, 3); BF1(4, 6); BFI(5, 7);
    BF1(0, 1); BF1(2, 3); BF1(4, 5); BF1(6, 7);
}

// 16-pt DFT, natural in, out v[p] = X[rev4(p)] (round-3 verified)
template<int SGN>
__device__ __forceinline__ void dft16(float2 v[16]) {
    constexpr float S  = (float)SGN;
    constexpr float RT = 0.70710678118654752440f;
    constexpr float C1 = 0.92387953251128675613f;
    constexpr float S1 = 0.38268343236508977173f;
    BF1(0, 8); BFW(1, 9, C1, S * S1); BFW(2, 10, RT, S * RT); BFW(3, 11, S1, S * C1);
    BFI(4, 12); BFW(5, 13, -S1, S * C1); BFW(6, 14, -RT, S * RT); BFW(7, 15, -C1, S * S1);
    BF1(0, 4); BFW(1, 5, RT, S * RT); BFI(2, 6); BFW(3, 7, -RT, S * RT);
    BF1(8, 12); BFW(9, 13, RT, S * RT); BFI(10, 14); BFW(11, 15, -RT, S * RT);
    BF1(0, 2); BFI(1, 3); BF1(4, 6); BFI(5, 7);
    BF1(8, 10); BFI(9, 11); BF1(12, 14); BFI(13, 15);
    BF1(0, 1); BF1(2, 3); BF1(4, 5); BF1(6, 7);
    BF1(8, 9); BF1(10, 11); BF1(12, 13); BF1(14, 15);
}

// ---------------- K1: forward FFT64 over t1 + inter twiddle ----------------
__global__ __launch_bounds__(512, 4) void k_fwd64(
    const float2* __restrict__ xp, float2* __restrict__ ws)
{
    __shared__ float2 lds[4096];
    constexpr int R3[8] = {0, 4, 2, 6, 1, 5, 3, 7};
    const int bid = blockIdx.x;
    const int jt = bid & 3;
    const int t2 = (bid >> 2) & 127;
    const int b  = bid >> 9;
    const int tid = threadIdx.x;
    const int sub = tid >> 6;     // tb in P1, ka in P2
    const int jj  = tid & 63;
    const int j   = jt * 64 + jj;

    float2 v[8];
    const size_t rowbase = ((size_t)b * 8192 + t2) * 256 + j;
#pragma unroll
    for (int ta = 0; ta < 8; ++ta)
        v[ta] = xp[rowbase + (size_t)(8 * ta + sub) * (128 * 256)];
    dft8<-1>(v);
    {
        float sn, cs; __sincosf(-TWO_PI * (float)sub / 64.0f, &sn, &cs);
        const float2 step = make_float2(cs, sn);
        float2 w = make_float2(1.f, 0.f);
#pragma unroll
        for (int ka = 0; ka < 8; ++ka) {
            const float2 val = (ka == 0) ? v[0] : cmul(v[R3[ka]], w);
            lds[(ka * 8 + sub) * 64 + jj] = val;
            w = cmul(w, step);
        }
    }
    __syncthreads();
    float2 g[8];
#pragma unroll
    for (int tb = 0; tb < 8; ++tb) g[tb] = lds[(sub * 8 + tb) * 64 + jj];
    dft8<-1>(g);
    {
        float sn, cs;
        __sincosf(-TWO_PI * (float)(t2 * sub) / 8192.0f, &sn, &cs);
        float2 w = make_float2(cs, sn);
        __sincosf(-TWO_PI * (float)t2 / 1024.0f, &sn, &cs);
        const float2 step = make_float2(cs, sn);
        const size_t obase = ((size_t)b * 64 * 128 + t2) * 256 + j;
#pragma unroll
        for (int kb = 0; kb < 8; ++kb) {
            const int k1 = sub + 8 * kb;
            ws[obase + (size_t)k1 * (128 * 256)] = cmul(g[R3[kb]], w);
            w = cmul(w, step);
        }
    }
}

// ------- K2: FFT128 over t2, untangle+filter+repack, iFFT128, twiddle -------
__global__ __launch_bounds__(512, 2) void k_mid128(
    float2* __restrict__ ws, const float2* __restrict__ Hp)
{
    __shared__ float2 Sm[64 * 133];
    constexpr int R3[8] = {0, 4, 2, 6, 1, 5, 3, 7};
    constexpr int R4[16] = {0, 8, 4, 12, 2, 10, 6, 14, 1, 9, 5, 13, 3, 11, 7, 15};
    const int bid = blockIdx.x;
    const int jt = bid & 7;
    const int c  = (bid >> 3) & 31;
    const int b  = bid >> 8;
    const int tid = threadIdx.x;
    const int k1A = c;
    const int k1B = (c == 0) ? 32 : 64 - c;
    const int j0 = jt * 32;

    // linear load: e = (k1sel*128 + t2)*32 + jj
#pragma unroll
    for (int m = 0; m < 16; ++m) {
        const int e = tid + m * 512;
        const int jj = e & 31;
        const int t2 = (e >> 5) & 127;
        const int ks = e >> 12;
        const int k1 = ks ? k1B : k1A;
        Sm[(ks * 32 + jj) * 133 + t2] =
            ws[(((size_t)b * 64 + k1) * 128 + t2) * 256 + j0 + jj];
    }
    __syncthreads();

    const int col = tid >> 3;   // 0..63 (k1sel*32 + jj)
    const int sub = tid & 7;    // tb / ka-pair selector
    float2* Sc = &Sm[col * 133];

    // fwd B1: dft16 over ta (pts 8*ta+sub), * w128^{-sub*ka} -> slot ka*8+sub
    {
        float2 v[16];
#pragma unroll
        for (int ta = 0; ta < 16; ++ta) v[ta] = Sc[8 * ta + sub];
        dft16<-1>(v);
        float sn, cs; __sincosf(-TWO_PI * (float)sub / 128.0f, &sn, &cs);
        const float2 step = make_float2(cs, sn);
        float2 w = make_float2(1.f, 0.f);
#pragma unroll
        for (int ka = 0; ka < 16; ++ka) {
            Sc[ka * 8 + sub] = (ka == 0) ? v[0] : cmul(v[R4[ka]], w);
            w = cmul(w, step);
        }
    }
    __syncthreads();

    // fwd B2: dft8 over tb for ka=sub, sub+8 -> spectrum at natural k2
    {
        float2 v[8], u[8];
#pragma unroll
        for (int tb = 0; tb < 8; ++tb) v[tb] = Sc[sub * 8 + tb];
#pragma unroll
        for (int tb = 0; tb < 8; ++tb) u[tb] = Sc[(sub + 8) * 8 + tb];
        dft8<-1>(v);
        { float2* t = u; float2* v = t; dft8<-1>(v); }  // dft8 on u
        __syncthreads();
#pragma unroll
        for (int kb = 0; kb < 8; ++kb) {
            Sc[sub + 16 * kb]     = v[R3[kb]];
            Sc[sub + 8 + 16 * kb] = u[R3[kb]];
        }
    }
    __syncthreads();

    // ---- untangle + filter + repack (bins k = k1 + 64*k2, 1/N folded) ----
    const float invN = 1.0f / 8192.0f;
    if (c != 0) {
#pragma unroll
        for (int m = 0; m < 8; ++m) {
            const int i = tid + m * 512;          // 4096 pairs
            const int sel = i >> 11;
            const int rem = i & 2047;
            const int k2 = rem & 63;
            const int jj = rem >> 6;
            const int col_lo = sel ? (32 + jj) : jj;
            const int col_hi = sel ? jj : (32 + jj);
            const int klo = (sel ? k1B : k1A) + 64 * k2;
            float2* Plo = &Sm[col_lo * 133 + k2];
            float2* Phi = &Sm[col_hi * 133 + 127 - k2];
            const int f0 = 2 * (j0 + jj);
            const float2 z1 = *Plo, z2 = *Phi;
            const float xar = 0.5f * (z1.x + z2.x), xai = 0.5f * (z1.y - z2.y);
            const float xbr = 0.5f * (z1.y + z2.y), xbi = 0.5f * (z2.x - z1.x);
            const float2 ha = Hp[(size_t)f0 * FREQ + klo];
            const float2 hb = Hp[(size_t)(f0 + 1) * FREQ + klo];
            const float har = ha.x * invN, hai = ha.y * invN;
            const float hbr = hb.x * invN, hbi = hb.y * invN;
            const float yar = xar * har - xai * hai, yai = xar * hai + xai * har;
            const float ybr = xbr * hbr - xbi * hbi, ybi = xbr * hbi + xbi * hbr;
            *Plo = make_float2(yar - ybi, yai + ybr);
            *Phi = make_float2(yar + ybi, ybr - yai);
        }
    } else {
        for (int m = 0; m < 9; ++m) {
            const int i = tid + m * 512;          // 2048 + 2080 items
            if (i >= 4128) break;
            int colx, slo, shi, klo, jj;
            bool special = false;
            if (i < 2048) {                       // k1 = 32 column
                const int k2 = i & 63; jj = i >> 6;
                colx = 32 + jj; slo = k2; shi = 127 - k2; klo = 32 + 64 * k2;
            } else {
                const int i2 = i - 2048;          // k1 = 0 column
                jj = i2 / 65;
                const int r = i2 - jj * 65;
                colx = jj;
                if (r == 0)       { slo = 0;  shi = 0;  klo = 0;    special = true; }
                else if (r == 64) { slo = 64; shi = 64; klo = 4096; special = true; }
                else              { slo = r; shi = 128 - r; klo = 64 * r; }
            }
            const int f0 = 2 * (j0 + jj);
            float2* Plo = &Sm[colx * 133 + slo];
            if (special) {
                const float2 z = *Plo;
                const float2 ha = Hp[(size_t)f0 * FREQ + klo];
                const float2 hb = Hp[(size_t)(f0 + 1) * FREQ + klo];
                *Plo = make_float2(z.x * ha.x * invN, z.y * hb.x * invN);
            } else {
                float2* Phi = &Sm[colx * 133 + shi];
                const float2 z1 = *Plo, z2 = *Phi;
                const float xar = 0.5f * (z1.x + z2.x), xai = 0.5f * (z1.y - z2.y);
                const float xbr = 0.5f * (z1.y + z2.y), xbi = 0.5f * (z2.x - z1.x);
                const float2 ha = Hp[(size_t)f0 * FREQ + klo];
                const float2 hb = Hp[(size_t)(f0 + 1) * FREQ + klo];
                const float har = ha.x * invN, hai = ha.y * invN;
                const float hbr = hb.x * invN, hbi = hb.y * invN;
                const float yar = xar * har - xai * hai, yai = xar * hai + xai * har;
                const float ybr = xbr * hbr - xbi * hbi, ybi = xbr * hbi + xbi * hbr;
                *Plo = make_float2(yar - ybi, yai + ybr);
                *Phi = make_float2(yar + ybi, ybr - yai);
            }
        }
    }
    __syncthreads();

    // inv iB1: dft8 over kb (slots ka+16*kb) for ka=sub,sub+8; * w128^{+tb*ka}
    {
        float2 v[8], u[8];
#pragma unroll
        for (int kb = 0; kb < 8; ++kb) v[kb] = Sc[sub + 16 * kb];
#pragma unroll
        for (int kb = 0; kb < 8; ++kb) u[kb] = Sc[sub + 8 + 16 * kb];
        dft8<1>(v);
        { float2* t = u; float2* v = t; dft8<1>(v); }
        float sn, cs;
        __sincosf(TWO_PI * (float)sub / 128.0f, &sn, &cs);
        const float2 st0 = make_float2(cs, sn);
        __sincosf(TWO_PI * (float)(sub + 8) / 128.0f, &sn, &cs);
        const float2 st1 = make_float2(cs, sn);
        float2 w0 = make_float2(1.f, 0.f), w1 = make_float2(1.f, 0.f);
        float2 o0[8], o1[8];
#pragma unroll
        for (int tb = 0; tb < 8; ++tb) {
            o0[tb] = (tb == 0) ? v[0] : cmul(v[R3[tb]], w0);
            o1[tb] = (tb == 0) ? u[0] : cmul(u[R3[tb]], w1);
            w0 = cmul(w0, st0); w1 = cmul(w1, st1);
        }
        __syncthreads();
#pragma unroll
        for (int tb = 0; tb < 8; ++tb) {
            Sc[sub * 8 + tb] = o0[tb];
            Sc[(sub + 8) * 8 + tb] = o1[tb];
        }
    }
    __syncthreads();

    // inv iB2: dft16 over ka (slots ka*8+sub), * w8192^{+(8ta+sub)k1}
    {
        const int k1c = (col >= 32) ? k1B : k1A;
        float2 v[16];
#pragma unroll
        for (int ka = 0; ka < 16; ++ka) v[ka] = Sc[ka * 8 + sub];
        dft16<1>(v);
        float sn, cs;
        __sincosf(TWO_PI * (float)(sub * k1c) / 8192.0f, &sn, &cs);
        float2 w = make_float2(cs, sn);
        __sincosf(TWO_PI * (float)k1c / 1024.0f, &sn, &cs);
        const float2 step = make_float2(cs, sn);
#pragma unroll
        for (int ta = 0; ta < 16; ++ta) {
            Sc[8 * ta + sub] = cmul(v[R4[ta]], w);
            w = cmul(w, step);
        }
    }
    __syncthreads();

    // linear store, in place
#pragma unroll
    for (int m = 0; m < 16; ++m) {
        const int e = tid + m * 512;
        const int jj = e & 31;
        const int t2 = (e >> 5) & 127;
        const int ks = e >> 12;
        const int k1 = ks ? k1B : k1A;
        ws[(((size_t)b * 64 + k1) * 128 + t2) * 256 + j0 + jj] =
            Sm[(ks * 32 + jj) * 133 + t2];
    }
}

// ---------------- K3: inverse FFT64 over k1, store y ----------------
__global__ __launch_bounds__(512, 4) void k_inv64(
    const float2* __restrict__ ws, float2* __restrict__ yp)
{
    __shared__ float2 lds[4096];
    constexpr int R3[8] = {0, 4, 2, 6, 1, 5, 3, 7};
    const int bid = blockIdx.x;
    const int jt = bid & 3;
    const int t2 = (bid >> 2) & 127;
    const int b  = bid >> 9;
    const int tid = threadIdx.x;
    const int sub = tid >> 6;     // kb in P1, ta in P2
    const int jj  = tid & 63;
    const int j   = jt * 64 + jj;

    float2 v[8];
    const size_t ibase = ((size_t)b * 64 * 128 + t2) * 256 + j;
#pragma unroll
    for (int ka = 0; ka < 8; ++ka)
        v[ka] = ws[ibase + (size_t)(8 * ka + sub) * (128 * 256)];
    dft8<1>(v);
    {
        float sn, cs; __sincosf(TWO_PI * (float)sub / 64.0f, &sn, &cs);
        const float2 step = make_float2(cs, sn);
        float2 w = make_float2(1.f, 0.f);
#pragma unroll
        for (int ta = 0; ta < 8; ++ta) {
            const float2 val = (ta == 0) ? v[0] : cmul(v[R3[ta]], w);
            lds[(ta * 8 + sub) * 64 + jj] = val;
            w = cmul(w, step);
        }
    }
    __syncthreads();
    float2 g[8];
#pragma unroll
    for (int kb = 0; kb < 8; ++kb) g[kb] = lds[(sub * 8 + kb) * 64 + jj];
    dft8<1>(g);
    const size_t rowbase = ((size_t)b * 8192 + t2) * 256 + j;
#pragma unroll
    for (int tb = 0; tb < 8; ++tb)
        yp[rowbase + (size_t)(sub + 8 * tb) * (128 * 256)] = g[R3[tb]];
}

extern "C" void kernel_launch(void* const* d_in, const int* in_sizes, int n_in,
                              void* d_out, int out_size, void* d_ws, size_t ws_size,
                              hipStream_t stream) {
    const float2* xp = (const float2*)d_in[0];
    const float2* Hp = (const float2*)d_in[1];
    float2* yp = (float2*)d_out;
    float2* ws = (float2*)d_ws;   // 8*64*128*256 float2 = 128 MB
    k_fwd64 <<<dim3(4096), dim3(512), 0, stream>>>(xp, ws);
    k_mid128<<<dim3(2048), dim3(512), 0, stream>>>(ws, Hp);
    k_inv64 <<<dim3(4096), dim3(512), 0, stream>>>(ws, yp);
}

// Round 8
// 372.563 us; speedup vs baseline: 1.1321x; 1.1321x over previous
//
#include <hip/hip_runtime.h>

// y = irfft(rfft(x, axis=1, ortho) * H, n=T, axis=1, ortho)
// x: [8, 8192, 512] f32, H: [512, 4097, 2] f32, y: [8, 8192, 512] f32
//
// Bailey 4-step, 8192 = 64 * 128, t = 128*t1 + t2, k = k1 + 64*k2.
//   K1: A[b,k1,t2,j] = sum_t1 z[b,128*t1+t2,j] w64^{-t1 k1} * w8192^{-t2 k1}
//   K2: per (b, {k1,64-k1}, 16 j): FFT128 over t2 (dft16 x dft8), untangle
//       real-pair spectra, filter (1/8192 folded), repack, iFFT128,
//       * w8192^{+t2 k1}, in-place in ws.
//   K3: z[b,t,j] = sum_k1 B[b,k1,t2,j] w64^{+t1 k1}; store y.
//
// Rounds 5-7 were infra failures (no data) — identical resubmit:
// K2 re-blocked for occupancy. 32 cols (16 j-pairs x 2 k1) x 128,
// 256 threads, LDS 34 KB -> 4 blocks/CU (was 68 KB / 1 block, 22% occ).

#define TWO_PI 6.28318530717958647692f
#define FREQ 4097

__device__ __forceinline__ float2 cmul(float2 a, float2 b) {
    return make_float2(a.x * b.x - a.y * b.y, a.x * b.y + a.y * b.x);
}

#define BF1(i0, i1) { float2 a = v[i0], b = v[i1]; \
    v[i0] = make_float2(a.x + b.x, a.y + b.y); \
    v[i1] = make_float2(a.x - b.x, a.y - b.y); }
#define BFI(i0, i1) { float2 a = v[i0], b = v[i1]; \
    v[i0] = make_float2(a.x + b.x, a.y + b.y); \
    float dr = a.x - b.x, di = a.y - b.y; \
    v[i1] = make_float2(-di * S, dr * S); }
#define BFW(i0, i1, wr, wi) { float2 a = v[i0], b = v[i1]; \
    v[i0] = make_float2(a.x + b.x, a.y + b.y); \
    float dr = a.x - b.x, di = a.y - b.y; \
    v[i1] = make_float2(dr * (wr) - di * (wi), dr * (wi) + di * (wr)); }

// 8-pt DFT, natural in, out v[p] = X[rev3(p)]; SGN=-1 fwd, +1 inv
template<int SGN>
__device__ __forceinline__ void dft8(float2* v) {
    constexpr float S  = (float)SGN;
    constexpr float RT = 0.70710678118654752440f;
    BF1(0, 4); BFW(1, 5, RT, S * RT); BFI(2, 6); BFW(3, 7, -RT, S * RT);
    BF1(0, 2); BFI(1, 3); BF1(4, 6); BFI(5, 7);
    BF1(0, 1); BF1(2, 3); BF1(4, 5); BF1(6, 7);
}

// 16-pt DFT, natural in, out v[p] = X[rev4(p)]
template<int SGN>
__device__ __forceinline__ void dft16(float2 v[16]) {
    constexpr float S  = (float)SGN;
    constexpr float RT = 0.70710678118654752440f;
    constexpr float C1 = 0.92387953251128675613f;
    constexpr float S1 = 0.38268343236508977173f;
    BF1(0, 8); BFW(1, 9, C1, S * S1); BFW(2, 10, RT, S * RT); BFW(3, 11, S1, S * C1);
    BFI(4, 12); BFW(5, 13, -S1, S * C1); BFW(6, 14, -RT, S * RT); BFW(7, 15, -C1, S * S1);
    BF1(0, 4); BFW(1, 5, RT, S * RT); BFI(2, 6); BFW(3, 7, -RT, S * RT);
    BF1(8, 12); BFW(9, 13, RT, S * RT); BFI(10, 14); BFW(11, 15, -RT, S * RT);
    BF1(0, 2); BFI(1, 3); BF1(4, 6); BFI(5, 7);
    BF1(8, 10); BFI(9, 11); BF1(12, 14); BFI(13, 15);
    BF1(0, 1); BF1(2, 3); BF1(4, 5); BF1(6, 7);
    BF1(8, 9); BF1(10, 11); BF1(12, 13); BF1(14, 15);
}

// ---------------- K1: forward FFT64 over t1 + inter twiddle ----------------
__global__ __launch_bounds__(512, 4) void k_fwd64(
    const float2* __restrict__ xp, float2* __restrict__ ws)
{
    __shared__ float2 lds[4096];
    constexpr int R3[8] = {0, 4, 2, 6, 1, 5, 3, 7};
    const int bid = blockIdx.x;
    const int jt = bid & 3;
    const int t2 = (bid >> 2) & 127;
    const int b  = bid >> 9;
    const int tid = threadIdx.x;
    const int sub = tid >> 6;     // tb in P1, ka in P2
    const int jj  = tid & 63;
    const int j   = jt * 64 + jj;

    float2 v[8];
    const size_t rowbase = ((size_t)b * 8192 + t2) * 256 + j;
#pragma unroll
    for (int ta = 0; ta < 8; ++ta)
        v[ta] = xp[rowbase + (size_t)(8 * ta + sub) * (128 * 256)];
    dft8<-1>(v);
    {
        float sn, cs; __sincosf(-TWO_PI * (float)sub / 64.0f, &sn, &cs);
        const float2 step = make_float2(cs, sn);
        float2 w = make_float2(1.f, 0.f);
#pragma unroll
        for (int ka = 0; ka < 8; ++ka) {
            const float2 val = (ka == 0) ? v[0] : cmul(v[R3[ka]], w);
            lds[(ka * 8 + sub) * 64 + jj] = val;
            w = cmul(w, step);
        }
    }
    __syncthreads();
    float2 g[8];
#pragma unroll
    for (int tb = 0; tb < 8; ++tb) g[tb] = lds[(sub * 8 + tb) * 64 + jj];
    dft8<-1>(g);
    {
        float sn, cs;
        __sincosf(-TWO_PI * (float)(t2 * sub) / 8192.0f, &sn, &cs);
        float2 w = make_float2(cs, sn);
        __sincosf(-TWO_PI * (float)t2 / 1024.0f, &sn, &cs);
        const float2 step = make_float2(cs, sn);
        const size_t obase = ((size_t)b * 64 * 128 + t2) * 256 + j;
#pragma unroll
        for (int kb = 0; kb < 8; ++kb) {
            const int k1 = sub + 8 * kb;
            ws[obase + (size_t)k1 * (128 * 256)] = cmul(g[R3[kb]], w);
            w = cmul(w, step);
        }
    }
}

// ------- K2: FFT128 over t2, untangle+filter+repack, iFFT128, twiddle -------
__global__ __launch_bounds__(256, 4) void k_mid128(
    float2* __restrict__ ws, const float2* __restrict__ Hp)
{
    __shared__ float2 Sm[32 * 133];   // 34048 B -> 4 blocks/CU
    constexpr int R3[8] = {0, 4, 2, 6, 1, 5, 3, 7};
    constexpr int R4[16] = {0, 8, 4, 12, 2, 10, 6, 14, 1, 9, 5, 13, 3, 11, 7, 15};
    const int bid = blockIdx.x;
    const int jt = bid & 15;
    const int c  = (bid >> 4) & 31;
    const int b  = bid >> 9;
    const int tid = threadIdx.x;
    const int k1A = c;
    const int k1B = (c == 0) ? 32 : 64 - c;
    const int j0 = jt * 16;

    // linear load: e = (ks*128 + t2)*16 + jj
#pragma unroll
    for (int m = 0; m < 16; ++m) {
        const int e = tid + m * 256;
        const int jj = e & 15;
        const int t2 = (e >> 4) & 127;
        const int ks = e >> 11;
        const int k1 = ks ? k1B : k1A;
        Sm[(ks * 16 + jj) * 133 + t2] =
            ws[(((size_t)b * 64 + k1) * 128 + t2) * 256 + j0 + jj];
    }
    __syncthreads();

    const int col = tid >> 3;   // 0..31 (ks*16 + jj)
    const int sub = tid & 7;
    float2* Sc = &Sm[col * 133];

    // fwd B1: dft16 over ta (pts 8*ta+sub), * w128^{-sub*ka} -> slot ka*8+sub
    {
        float2 v[16];
#pragma unroll
        for (int ta = 0; ta < 16; ++ta) v[ta] = Sc[8 * ta + sub];
        dft16<-1>(v);
        float sn, cs; __sincosf(-TWO_PI * (float)sub / 128.0f, &sn, &cs);
        const float2 step = make_float2(cs, sn);
        float2 w = make_float2(1.f, 0.f);
#pragma unroll
        for (int ka = 0; ka < 16; ++ka) {
            Sc[ka * 8 + sub] = (ka == 0) ? v[0] : cmul(v[R4[ka]], w);
            w = cmul(w, step);
        }
    }
    __syncthreads();

    // fwd B2: dft8 over tb for ka=sub, sub+8 -> spectrum at natural k2
    {
        float2 v[8], u[8];
#pragma unroll
        for (int tb = 0; tb < 8; ++tb) v[tb] = Sc[sub * 8 + tb];
#pragma unroll
        for (int tb = 0; tb < 8; ++tb) u[tb] = Sc[(sub + 8) * 8 + tb];
        dft8<-1>(v);
        { float2* t = u; float2* v = t; dft8<-1>(v); }  // dft8 on u
        __syncthreads();
#pragma unroll
        for (int kb = 0; kb < 8; ++kb) {
            Sc[sub + 16 * kb]     = v[R3[kb]];
            Sc[sub + 8 + 16 * kb] = u[R3[kb]];
        }
    }
    __syncthreads();

    // ---- untangle + filter + repack (bins k = k1 + 64*k2, 1/N folded) ----
    const float invN = 1.0f / 8192.0f;
    if (c != 0) {
#pragma unroll
        for (int m = 0; m < 8; ++m) {
            const int i = tid + m * 256;          // 2048 pairs
            const int sel = i >> 10;
            const int k2 = i & 63;
            const int jj = (i >> 6) & 15;
            const int col_lo = sel * 16 + jj;
            const int col_hi = (1 - sel) * 16 + jj;
            const int klo = (sel ? k1B : k1A) + 64 * k2;
            float2* Plo = &Sm[col_lo * 133 + k2];
            float2* Phi = &Sm[col_hi * 133 + 127 - k2];
            const int f0 = 2 * (j0 + jj);
            const float2 z1 = *Plo, z2 = *Phi;
            const float xar = 0.5f * (z1.x + z2.x), xai = 0.5f * (z1.y - z2.y);
            const float xbr = 0.5f * (z1.y + z2.y), xbi = 0.5f * (z2.x - z1.x);
            const float2 ha = Hp[(size_t)f0 * FREQ + klo];
            const float2 hb = Hp[(size_t)(f0 + 1) * FREQ + klo];
            const float har = ha.x * invN, hai = ha.y * invN;
            const float hbr = hb.x * invN, hbi = hb.y * invN;
            const float yar = xar * har - xai * hai, yai = xar * hai + xai * har;
            const float ybr = xbr * hbr - xbi * hbi, ybi = xbr * hbi + xbi * hbr;
            *Plo = make_float2(yar - ybi, yai + ybr);
            *Phi = make_float2(yar + ybi, ybr - yai);
        }
    } else {
        for (int m = 0; m < 9; ++m) {
            const int i = tid + m * 256;          // 1024 + 1040 items
            if (i >= 2064) break;
            int colx, slo, shi, klo, jj;
            bool special = false;
            if (i < 1024) {                       // k1 = 32 column (self-paired)
                const int k2 = i & 63; jj = i >> 6;
                colx = 16 + jj; slo = k2; shi = 127 - k2; klo = 32 + 64 * k2;
            } else {
                const int i2 = i - 1024;          // k1 = 0 column
                jj = i2 / 65;
                const int r = i2 - jj * 65;
                colx = jj;
                if (r == 0)       { slo = 0;  shi = 0;  klo = 0;    special = true; }
                else if (r == 64) { slo = 64; shi = 64; klo = 4096; special = true; }
                else              { slo = r; shi = 128 - r; klo = 64 * r; }
            }
            const int f0 = 2 * (j0 + jj);
            float2* Plo = &Sm[colx * 133 + slo];
            if (special) {
                const float2 z = *Plo;
                const float2 ha = Hp[(size_t)f0 * FREQ + klo];
                const float2 hb = Hp[(size_t)(f0 + 1) * FREQ + klo];
                *Plo = make_float2(z.x * ha.x * invN, z.y * hb.x * invN);
            } else {
                float2* Phi = &Sm[colx * 133 + shi];
                const float2 z1 = *Plo, z2 = *Phi;
                const float xar = 0.5f * (z1.x + z2.x), xai = 0.5f * (z1.y - z2.y);
                const float xbr = 0.5f * (z1.y + z2.y), xbi = 0.5f * (z2.x - z1.x);
                const float2 ha = Hp[(size_t)f0 * FREQ + klo];
                const float2 hb = Hp[(size_t)(f0 + 1) * FREQ + klo];
                const float har = ha.x * invN, hai = ha.y * invN;
                const float hbr = hb.x * invN, hbi = hb.y * invN;
                const float yar = xar * har - xai * hai, yai = xar * hai + xai * har;
                const float ybr = xbr * hbr - xbi * hbi, ybi = xbr * hbi + xbi * hbr;
                *Plo = make_float2(yar - ybi, yai + ybr);
                *Phi = make_float2(yar + ybi, ybr - yai);
            }
        }
    }
    __syncthreads();

    // inv iB1: dft8 over kb (slots ka+16*kb) for ka=sub,sub+8; * w128^{+tb*ka}
    {
        float2 v[8], u[8];
#pragma unroll
        for (int kb = 0; kb < 8; ++kb) v[kb] = Sc[sub + 16 * kb];
#pragma unroll
        for (int kb = 0; kb < 8; ++kb) u[kb] = Sc[sub + 8 + 16 * kb];
        dft8<1>(v);
        { float2* t = u; float2* v = t; dft8<1>(v); }
        float sn, cs;
        __sincosf(TWO_PI * (float)sub / 128.0f, &sn, &cs);
        const float2 st0 = make_float2(cs, sn);
        __sincosf(TWO_PI * (float)(sub + 8) / 128.0f, &sn, &cs);
        const float2 st1 = make_float2(cs, sn);
        float2 w0 = make_float2(1.f, 0.f), w1 = make_float2(1.f, 0.f);
        float2 o0[8], o1[8];
#pragma unroll
        for (int tb = 0; tb < 8; ++tb) {
            o0[tb] = (tb == 0) ? v[0] : cmul(v[R3[tb]], w0);
            o1[tb] = (tb == 0) ? u[0] : cmul(u[R3[tb]], w1);
            w0 = cmul(w0, st0); w1 = cmul(w1, st1);
        }
        __syncthreads();
#pragma unroll
        for (int tb = 0; tb < 8; ++tb) {
            Sc[sub * 8 + tb] = o0[tb];
            Sc[(sub + 8) * 8 + tb] = o1[tb];
        }
    }
    __syncthreads();

    // inv iB2: dft16 over ka (slots ka*8+sub), * w8192^{+(8ta+sub)k1}
    {
        const int k1c = (col >= 16) ? k1B : k1A;
        float2 v[16];
#pragma unroll
        for (int ka = 0; ka < 16; ++ka) v[ka] = Sc[ka * 8 + sub];
        dft16<1>(v);
        float sn, cs;
        __sincosf(TWO_PI * (float)(sub * k1c) / 8192.0f, &sn, &cs);
        float2 w = make_float2(cs, sn);
        __sincosf(TWO_PI * (float)k1c / 1024.0f, &sn, &cs);
        const float2 step = make_float2(cs, sn);
#pragma unroll
        for (int ta = 0; ta < 16; ++ta) {
            Sc[8 * ta + sub] = cmul(v[R4[ta]], w);
            w = cmul(w, step);
        }
    }
    __syncthreads();

    // linear store, in place
#pragma unroll
    for (int m = 0; m < 16; ++m) {
        const int e = tid + m * 256;
        const int jj = e & 15;
        const int t2 = (e >> 4) & 127;
        const int ks = e >> 11;
        const int k1 = ks ? k1B : k1A;
        ws[(((size_t)b * 64 + k1) * 128 + t2) * 256 + j0 + jj] =
            Sm[(ks * 16 + jj) * 133 + t2];
    }
}

// ---------------- K3: inverse FFT64 over k1, store y ----------------
__global__ __launch_bounds__(512, 4) void k_inv64(
    const float2* __restrict__ ws, float2* __restrict__ yp)
{
    __shared__ float2 lds[4096];
    constexpr int R3[8] = {0, 4, 2, 6, 1, 5, 3, 7};
    const int bid = blockIdx.x;
    const int jt = bid & 3;
    const int t2 = (bid >> 2) & 127;
    const int b  = bid >> 9;
    const int tid = threadIdx.x;
    const int sub = tid >> 6;     // kb in P1, ta in P2
    const int jj  = tid & 63;
    const int j   = jt * 64 + jj;

    float2 v[8];
    const size_t ibase = ((size_t)b * 64 * 128 + t2) * 256 + j;
#pragma unroll
    for (int ka = 0; ka < 8; ++ka)
        v[ka] = ws[ibase + (size_t)(8 * ka + sub) * (128 * 256)];
    dft8<1>(v);
    {
        float sn, cs; __sincosf(TWO_PI * (float)sub / 64.0f, &sn, &cs);
        const float2 step = make_float2(cs, sn);
        float2 w = make_float2(1.f, 0.f);
#pragma unroll
        for (int ta = 0; ta < 8; ++ta) {
            const float2 val = (ta == 0) ? v[0] : cmul(v[R3[ta]], w);
            lds[(ta * 8 + sub) * 64 + jj] = val;
            w = cmul(w, step);
        }
    }
    __syncthreads();
    float2 g[8];
#pragma unroll
    for (int kb = 0; kb < 8; ++kb) g[kb] = lds[(sub * 8 + kb) * 64 + jj];
    dft8<1>(g);
    const size_t rowbase = ((size_t)b * 8192 + t2) * 256 + j;
#pragma unroll
    for (int tb = 0; tb < 8; ++tb)
        yp[rowbase + (size_t)(sub + 8 * tb) * (128 * 256)] = g[R3[tb]];
}

extern "C" void kernel_launch(void* const* d_in, const int* in_sizes, int n_in,
                              void* d_out, int out_size, void* d_ws, size_t ws_size,
                              hipStream_t stream) {
    const float2* xp = (const float2*)d_in[0];
    const float2* Hp = (const float2*)d_in[1];
    float2* yp = (float2*)d_out;
    float2* ws = (float2*)d_ws;   // 8*64*128*256 float2 = 128 MB
    k_fwd64 <<<dim3(4096), dim3(512), 0, stream>>>(xp, ws);
    k_mid128<<<dim3(4096), dim3(256), 0, stream>>>(ws, Hp);
    k_inv64 <<<dim3(4096), dim3(512), 0, stream>>>(ws, yp);
}